// Round 5
// baseline (339.159 us; speedup 1.0000x reference)
//
#include <hip/hip_runtime.h>
#include <math.h>

// Problem constants (fixed by the reference): B=8, C=3, K=4, H=512, W=512
// HW/4 = 65536 float4 per plane. total = B*C*HW/4 = 1572864 = 1536 * 1024 exactly.

typedef float f32x4 __attribute__((ext_vector_type(4)));

#define HALF_LOG2E 0.7213475204444817f
#define NI 4              // items per thread; 2-deep software pipeline
#define HWQ 65536         // H*W/4

struct Item {
    f32x4 x;
    f32x4 U[4], V[4], N[4];
};

__device__ __forceinline__ int item_base(int t) {
    const int bc = t >> 16;         // (b*C + c)
    const int p4 = t & 65535;       // pixel/4 within plane
    return bc * 4 * HWQ + p4;       // plane (bc*K + k), k stride = HWQ
}

__device__ __forceinline__ void load_item(
    Item& it, int t,
    const f32x4* __restrict__ x4, const f32x4* __restrict__ U4,
    const f32x4* __restrict__ V4, const f32x4* __restrict__ N4)
{
    const int base = item_base(t);
    it.x = x4[t];
#pragma unroll
    for (int k = 0; k < 4; ++k) {
        it.U[k] = U4[base + k * HWQ];
        it.V[k] = V4[base + k * HWQ];
        it.N[k] = N4[base + k * HWQ];
    }
}

__device__ __forceinline__ void compute_store_item(
    Item& it, int t, float nTotal,
    f32x4* __restrict__ Uo, f32x4* __restrict__ Vo,
    f32x4* __restrict__ No, f32x4* __restrict__ Po)
{
    const int base = item_base(t);
    f32x4 Pw;

#pragma unroll
    for (int j = 0; j < 4; ++j) {       // the 4 packed w-pixels
        const float xs = it.x[j];

        float u[4], vv[4], nn[4];
        float nsum = 0.f;
#pragma unroll
        for (int k = 0; k < 4; ++k) {
            u[k]  = it.U[k][j];
            vv[k] = it.V[k][j];
            nn[k] = it.N[k][j];
            nsum += nn[k];
        }
        const float inv_nsum = __builtin_amdgcn_rcpf(nsum);

        // base-2 logits: l2 = log2(Nn * invS) - 0.5*log2(e)*z^2
        // softmax over k is invariant to the uniform base change.
        float l2[4], Nn[4], Xd[4];
        float prob = 0.f;
        float m = -1e30f;
#pragma unroll
        for (int k = 0; k < 4; ++k) {
            const float uu   = u[k];
            const float s2   = fmaxf(vv[k] - uu * uu, 0.01f);
            const float invS = __builtin_amdgcn_rsqf(s2);
            const float xd   = xs - uu;
            const float z    = xd * invS;
            const float P    = nn[k] * inv_nsum;        // Nn / nTotal
            const float nnk  = nTotal * P;              // Nn
            const float cdf  = 0.5f * (1.0f + erff(fabsf(z) * 0.70710678118654752440f));
            prob += P * cdf;
            const float l = __builtin_amdgcn_logf(nnk * invS) - HALF_LOG2E * z * z;
            l2[k] = l;
            m = fmaxf(m, l);
            Nn[k] = nnk;
            Xd[k] = xd;
        }

        float g[4], gs = 0.f;
#pragma unroll
        for (int k = 0; k < 4; ++k) { g[k] = __builtin_amdgcn_exp2f(l2[k] - m); gs += g[k]; }
        const float invgs = __builtin_amdgcn_rcpf(gs);
        const float x2 = xs * xs;

#pragma unroll
        for (int k = 0; k < 4; ++k) {
            const float Gamma = g[k] * invgs;
            const float Nout  = Nn[k] + Gamma;
            const float Eta   = Gamma * __builtin_amdgcn_rcpf(Nout);
            it.U[k][j] = u[k]  + Eta * Xd[k];
            it.V[k][j] = vv[k] + Eta * (x2 - vv[k]);
            it.N[k][j] = Nout;
        }
        Pw[j] = prob;
    }

#pragma unroll
    for (int k = 0; k < 4; ++k) {
        __builtin_nontemporal_store(it.U[k], &Uo[base + k * HWQ]);
        __builtin_nontemporal_store(it.V[k], &Vo[base + k * HWQ]);
        __builtin_nontemporal_store(it.N[k], &No[base + k * HWQ]);
    }
    __builtin_nontemporal_store(Pw, &Po[t]);
}

__global__ __launch_bounds__(256, 4) void gmm_kernel(
    const f32x4* __restrict__ x4,
    const f32x4* __restrict__ U4,
    const f32x4* __restrict__ V4,
    const f32x4* __restrict__ N4,
    const float* __restrict__ eta_p,
    float* __restrict__ out,
    int total,      // B*C*HW/4 vec4 work items (grid covers exactly)
    int ckhw4)      // B*C*K*HW/4 (one output tensor, in float4 units)
{
    const float nTotal = 1.0f / eta_p[0] - 1.0f;   // 99

    f32x4* Uo = (f32x4*)out;
    f32x4* Vo = Uo + ckhw4;
    f32x4* No = Vo + ckhw4;
    f32x4* Po = No + ckhw4;

    const int t0 = blockIdx.x * (256 * NI) + threadIdx.x;

    // 2-deep software pipeline over NI items, fully unrolled so the
    // double-buffer index is compile-time constant (no scratch).
    Item buf[2];
    load_item(buf[0], t0, x4, U4, V4, N4);

#pragma unroll
    for (int s = 0; s < NI; ++s) {
        if (s + 1 < NI)
            load_item(buf[(s + 1) & 1], t0 + (s + 1) * 256, x4, U4, V4, N4);
        compute_store_item(buf[s & 1], t0 + s * 256, nTotal, Uo, Vo, No, Po);
    }
}

extern "C" void kernel_launch(void* const* d_in, const int* in_sizes, int n_in,
                              void* d_out, int out_size, void* d_ws, size_t ws_size,
                              hipStream_t stream) {
    const f32x4* x  = (const f32x4*)d_in[0];
    const f32x4* U  = (const f32x4*)d_in[1];
    const f32x4* V  = (const f32x4*)d_in[2];
    const f32x4* N  = (const f32x4*)d_in[3];
    const float* eta = (const float*)d_in[4];
    float* out = (float*)d_out;

    const int total = in_sizes[0] / 4;   // 1572864
    const int ckhw4 = in_sizes[1] / 4;   // 6291456

    const int block = 256;
    const int items_per_block = block * NI;                            // 1024
    const int grid = (total + items_per_block - 1) / items_per_block;  // 1536 exact
    gmm_kernel<<<grid, block, 0, stream>>>(x, U, V, N, eta, out, total, ckhw4);
}

// Round 6
// 226.743 us; speedup vs baseline: 1.4958x; 1.4958x over previous
//
#include <hip/hip_runtime.h>
#include <math.h>

// Problem constants (fixed by the reference): B=8, C=3, K=4, H=512, W=512
// HW/4 = 65536 float4 per plane. total = B*C*HW/4 = 1572864 = 3072 * 512 exactly.

typedef float f32x4 __attribute__((ext_vector_type(4)));

#define HALF_LOG2E 0.7213475204444817f   // log2(e)/2
#define HWQ 65536                        // H*W/4

struct Item {
    f32x4 x;
    f32x4 U[4], V[4], N[4];
};

__device__ __forceinline__ int item_base(int t) {
    const int bc = t >> 16;         // (b*C + c)
    const int p4 = t & 65535;       // pixel/4 within plane
    return bc * 4 * HWQ + p4;       // plane (bc*K + k), k stride = HWQ
}

__device__ __forceinline__ void load_item(
    Item& it, int t,
    const f32x4* __restrict__ x4, const f32x4* __restrict__ U4,
    const f32x4* __restrict__ V4, const f32x4* __restrict__ N4)
{
    const int base = item_base(t);
    it.x = x4[t];
#pragma unroll
    for (int k = 0; k < 4; ++k) {
        it.U[k] = U4[base + k * HWQ];
        it.V[k] = V4[base + k * HWQ];
        it.N[k] = N4[base + k * HWQ];
    }
}

__device__ __forceinline__ void compute_store_item(
    Item& it, int t, float nTotal,
    f32x4* __restrict__ Uo, f32x4* __restrict__ Vo,
    f32x4* __restrict__ No, f32x4* __restrict__ Po)
{
    const int base = item_base(t);
    f32x4 Pw;

    // Abramowitz-Stegun 7.1.26 coefficients, pre-halved so that
    // 0.5*(1+erf(y)) = 1 - polyh(t)*exp(-y^2), t = 1/(1+p*y).  |err|<=1e-7.
    const float pC  = 0.3275911f;
    const float a1h = 0.254829592f * 0.5f;
    const float a2h = -0.284496736f * 0.5f;
    const float a3h = 1.421413741f * 0.5f;
    const float a4h = -1.453152027f * 0.5f;
    const float a5h = 1.061405429f * 0.5f;

#pragma unroll
    for (int j = 0; j < 4; ++j) {       // the 4 packed w-pixels
        const float xs = it.x[j];

        float u[4], vv[4], nn[4];
        float nsum = 0.f;
#pragma unroll
        for (int k = 0; k < 4; ++k) {
            u[k]  = it.U[k][j];
            vv[k] = it.V[k][j];
            nn[k] = it.N[k][j];
            nsum += nn[k];
        }
        const float inv_nsum = __builtin_amdgcn_rcpf(nsum);

        // base-2 logits: l2 = log2(Nn * invS) - zz, zz = log2(e)/2 * z^2.
        // exp(-z^2/2) = exp2(-zz) is shared between the logit and the cdf.
        float l2[4], Nn[4], Xd[4];
        float prob = 0.f;
        float m = -1e30f;
#pragma unroll
        for (int k = 0; k < 4; ++k) {
            const float uu   = u[k];
            const float s2   = fmaxf(vv[k] - uu * uu, 0.01f);
            const float invS = __builtin_amdgcn_rsqf(s2);
            const float xd   = xs - uu;
            const float z    = xd * invS;
            const float zz   = HALF_LOG2E * z * z;
            const float P    = nn[k] * inv_nsum;        // Nn / nTotal
            const float nnk  = nTotal * P;              // Nn

            // cdf(|z|) = 1 - polyh(t)*exp2(-zz), t = 1/(1 + p*|z|/sqrt(2))
            const float y    = fabsf(z) * 0.70710678118654752440f;
            const float tt   = __builtin_amdgcn_rcpf(fmaf(pC, y, 1.0f));
            const float e    = __builtin_amdgcn_exp2f(-zz);
            float poly = fmaf(a5h, tt, a4h);
            poly = fmaf(poly, tt, a3h);
            poly = fmaf(poly, tt, a2h);
            poly = fmaf(poly, tt, a1h);
            poly = poly * tt;
            const float cdf  = fmaf(-poly, e, 1.0f);
            prob = fmaf(P, cdf, prob);

            const float l = __builtin_amdgcn_logf(nnk * invS) - zz;
            l2[k] = l;
            m = fmaxf(m, l);
            Nn[k] = nnk;
            Xd[k] = xd;
        }

        float g[4], gs = 0.f;
#pragma unroll
        for (int k = 0; k < 4; ++k) { g[k] = __builtin_amdgcn_exp2f(l2[k] - m); gs += g[k]; }
        const float invgs = __builtin_amdgcn_rcpf(gs);
        const float x2 = xs * xs;

#pragma unroll
        for (int k = 0; k < 4; ++k) {
            const float Gamma = g[k] * invgs;
            const float Nout  = Nn[k] + Gamma;
            const float Eta   = Gamma * __builtin_amdgcn_rcpf(Nout);
            it.U[k][j] = u[k]  + Eta * Xd[k];
            it.V[k][j] = vv[k] + Eta * (x2 - vv[k]);
            it.N[k][j] = Nout;
        }
        Pw[j] = prob;
    }

#pragma unroll
    for (int k = 0; k < 4; ++k) {
        __builtin_nontemporal_store(it.U[k], &Uo[base + k * HWQ]);
        __builtin_nontemporal_store(it.V[k], &Vo[base + k * HWQ]);
        __builtin_nontemporal_store(it.N[k], &No[base + k * HWQ]);
    }
    __builtin_nontemporal_store(Pw, &Po[t]);
}

__global__ void gmm_kernel(
    const f32x4* __restrict__ x4,
    const f32x4* __restrict__ U4,
    const f32x4* __restrict__ V4,
    const f32x4* __restrict__ N4,
    const float* __restrict__ eta_p,
    float* __restrict__ out,
    int total,      // B*C*HW/4 vec4 work items (grid covers exactly)
    int ckhw4)      // B*C*K*HW/4 (one output tensor, in float4 units)
{
    const float nTotal = 1.0f / eta_p[0] - 1.0f;   // 99

    f32x4* Uo = (f32x4*)out;
    f32x4* Vo = Uo + ckhw4;
    f32x4* No = Vo + ckhw4;
    f32x4* Po = No + ckhw4;

    const int t0 = blockIdx.x * 512 + threadIdx.x;   // NI=2 items per thread

    // 2-deep pipeline with NAMED buffers (no runtime indexing -> no scratch).
    // All 26 loads issue before the first compute; b's latency hides under
    // a's compute+store.
    Item a, b;
    load_item(a, t0,       x4, U4, V4, N4);
    load_item(b, t0 + 256, x4, U4, V4, N4);

    compute_store_item(a, t0,       nTotal, Uo, Vo, No, Po);
    compute_store_item(b, t0 + 256, nTotal, Uo, Vo, No, Po);
}

extern "C" void kernel_launch(void* const* d_in, const int* in_sizes, int n_in,
                              void* d_out, int out_size, void* d_ws, size_t ws_size,
                              hipStream_t stream) {
    const f32x4* x  = (const f32x4*)d_in[0];
    const f32x4* U  = (const f32x4*)d_in[1];
    const f32x4* V  = (const f32x4*)d_in[2];
    const f32x4* N  = (const f32x4*)d_in[3];
    const float* eta = (const float*)d_in[4];
    float* out = (float*)d_out;

    const int total = in_sizes[0] / 4;   // 1572864
    const int ckhw4 = in_sizes[1] / 4;   // 6291456

    const int block = 256;
    const int grid = total / 512;        // 3072, exact
    gmm_kernel<<<grid, block, 0, stream>>>(x, U, V, N, eta, out, total, ckhw4);
}

// Round 7
// 112.403 us; speedup vs baseline: 3.0173x; 2.0172x over previous
//
#include <hip/hip_runtime.h>
#include <math.h>

// Problem constants (fixed by the reference): B=8, C=3, K=4, H=512, W=512
// HW = 262144. Total pixels = B*C*HW = 6291456 = 24576 * 256 exactly.
// Scalar kernel: 1 pixel per thread -> minimal register state, max occupancy.
// Wave loads are 64 lanes x 4B = 256B per stream, fully coalesced.

#define HALF_LOG2E 0.7213475204444817f   // log2(e)/2
#define HW 262144

__global__ void gmm_kernel(
    const float* __restrict__ x_,
    const float* __restrict__ U_,
    const float* __restrict__ V_,
    const float* __restrict__ N_,
    const float* __restrict__ eta_p,
    float* __restrict__ out,
    int ckhw)       // B*C*K*HW = one output tensor in floats
{
    const int p  = blockIdx.x * 256 + threadIdx.x;   // pixel id, grid exact
    const int bc = p >> 18;                          // (b*C + c)
    const int off = p & (HW - 1);
    const int base = bc * 4 * HW + off;              // plane (bc*K+k), k stride = HW

    const float nTotal = 1.0f / eta_p[0] - 1.0f;     // 99

    float* Uo = out;
    float* Vo = Uo + ckhw;
    float* No = Vo + ckhw;
    float* Po = No + ckhw;

    // ---- loads: 13 coalesced scalar streams ----
    const float xs = x_[p];
    float u[4], vv[4], nn[4];
#pragma unroll
    for (int k = 0; k < 4; ++k) {
        u[k]  = U_[base + k * HW];
        vv[k] = V_[base + k * HW];
        nn[k] = N_[base + k * HW];
    }

    float nsum = (nn[0] + nn[1]) + (nn[2] + nn[3]);
    const float inv_nsum = __builtin_amdgcn_rcpf(nsum);

    // Abramowitz-Stegun 7.1.26, pre-halved: 0.5*(1+erf(y)) = 1 - polyh(t)*exp(-y^2)
    const float pC  = 0.3275911f;
    const float a1h = 0.254829592f * 0.5f;
    const float a2h = -0.284496736f * 0.5f;
    const float a3h = 1.421413741f * 0.5f;
    const float a4h = -1.453152027f * 0.5f;
    const float a5h = 1.061405429f * 0.5f;

    // base-2 logits: l2 = log2(Nn*invS) - zz, zz = log2(e)/2 * z^2
    float l2[4], Nn[4], Xd[4];
    float prob = 0.f;
    float m = -1e30f;
#pragma unroll
    for (int k = 0; k < 4; ++k) {
        const float uu   = u[k];
        const float s2   = fmaxf(vv[k] - uu * uu, 0.01f);
        const float invS = __builtin_amdgcn_rsqf(s2);
        const float xd   = xs - uu;
        const float z    = xd * invS;
        const float zz   = HALF_LOG2E * z * z;
        const float P    = nn[k] * inv_nsum;        // Nn / nTotal
        const float nnk  = nTotal * P;              // Nn

        const float y    = fabsf(z) * 0.70710678118654752440f;
        const float tt   = __builtin_amdgcn_rcpf(fmaf(pC, y, 1.0f));
        const float e    = __builtin_amdgcn_exp2f(-zz);
        float poly = fmaf(a5h, tt, a4h);
        poly = fmaf(poly, tt, a3h);
        poly = fmaf(poly, tt, a2h);
        poly = fmaf(poly, tt, a1h);
        poly = poly * tt;
        const float cdf  = fmaf(-poly, e, 1.0f);
        prob = fmaf(P, cdf, prob);

        const float l = __builtin_amdgcn_logf(nnk * invS) - zz;
        l2[k] = l;
        m = fmaxf(m, l);
        Nn[k] = nnk;
        Xd[k] = xd;
    }

    float g[4];
#pragma unroll
    for (int k = 0; k < 4; ++k) g[k] = __builtin_amdgcn_exp2f(l2[k] - m);
    const float gs = (g[0] + g[1]) + (g[2] + g[3]);
    const float invgs = __builtin_amdgcn_rcpf(gs);
    const float x2 = xs * xs;

#pragma unroll
    for (int k = 0; k < 4; ++k) {
        const float Gamma = g[k] * invgs;
        const float Nout  = Nn[k] + Gamma;
        const float Eta   = Gamma * __builtin_amdgcn_rcpf(Nout);
        __builtin_nontemporal_store(u[k]  + Eta * Xd[k],        &Uo[base + k * HW]);
        __builtin_nontemporal_store(vv[k] + Eta * (x2 - vv[k]), &Vo[base + k * HW]);
        __builtin_nontemporal_store(Nout,                        &No[base + k * HW]);
    }
    __builtin_nontemporal_store(prob, &Po[p]);
}

extern "C" void kernel_launch(void* const* d_in, const int* in_sizes, int n_in,
                              void* d_out, int out_size, void* d_ws, size_t ws_size,
                              hipStream_t stream) {
    const float* x  = (const float*)d_in[0];
    const float* U  = (const float*)d_in[1];
    const float* V  = (const float*)d_in[2];
    const float* N  = (const float*)d_in[3];
    const float* eta = (const float*)d_in[4];
    float* out = (float*)d_out;

    const int totalPix = in_sizes[0];    // 6291456
    const int ckhw     = in_sizes[1];    // 25165824

    const int block = 256;
    const int grid  = totalPix / block;  // 24576, exact
    gmm_kernel<<<grid, block, 0, stream>>>(x, U, V, N, eta, out, ckhw);
}